// Round 5
// baseline (402.905 us; speedup 1.0000x reference)
//
#include <hip/hip_runtime.h>
#include <hip/hip_cooperative_groups.h>

namespace cg = cooperative_groups;

// Problem constants
constexpr int B      = 16384;
constexpr int D_IN   = 1024;
constexpr int D_OUT  = 256;
constexpr int NCLS   = 1000;
constexpr int CPAD   = 1024;   // padded class count

// ---------------- workspace layout (byte offsets) ----------------
constexpr size_t OFF_XB   = 0;                                    // B*D_IN bf16   (32 MB)
constexpr size_t OFF_WB   = OFF_XB  + (size_t)B * D_IN * 2;       // 512*D_IN bf16 (1 MB)
constexpr size_t OFF_S    = OFF_WB  + (size_t)512 * D_IN * 2;     // CPAD*D_IN f32 (4 MB)
constexpr size_t OFF_Z    = OFF_S   + (size_t)CPAD * D_IN * 4;    // CPAD*D_OUT f32 (1 MB)
constexpr size_t OFF_T    = OFF_Z   + (size_t)CPAD * D_OUT * 4;   // D_IN f32
constexpr size_t OFF_CNT  = OFF_T   + (size_t)D_IN * 4;           // CPAD int
constexpr size_t OFF_OFFS = OFF_CNT + (size_t)CPAD * 4;           // CPAD int
constexpr size_t OFF_CUR  = OFF_OFFS+ (size_t)CPAD * 4;           // CPAD int (unused)
constexpr size_t OFF_ROWL = OFF_CUR + (size_t)CPAD * 4;           // B int

typedef short bf16x8 __attribute__((ext_vector_type(8)));
typedef float f32x4  __attribute__((ext_vector_type(4)));

// fp32 -> bf16 round-to-nearest-even
__device__ __forceinline__ unsigned short f2bf(float f) {
    unsigned int u = __float_as_uint(f);
    return (unsigned short)((u + 0x7FFFu + ((u >> 16) & 1u)) >> 16);
}

__device__ __forceinline__ void cvt8(const float4& a, const float4& b, unsigned short* dst) {
    union { unsigned short u[8]; bf16x8 v; } r;
    r.u[0] = f2bf(a.x); r.u[1] = f2bf(a.y); r.u[2] = f2bf(a.z); r.u[3] = f2bf(a.w);
    r.u[4] = f2bf(b.x); r.u[5] = f2bf(b.y); r.u[6] = f2bf(b.z); r.u[7] = f2bf(b.w);
    *(bf16x8*)dst = r.v;
}

__device__ __forceinline__ ushort4 f2bf4(const float4& a) {
    ushort4 r;
    r.x = f2bf(a.x); r.y = f2bf(a.y); r.z = f2bf(a.z); r.w = f2bf(a.w);
    return r;
}

// async global->LDS, 16B/lane; lds dst = wave-uniform base (+lane*16 implied by HW)
__device__ __forceinline__ void async16(const unsigned short* g, unsigned short* l) {
    __builtin_amdgcn_global_load_lds(
        (const __attribute__((address_space(1))) void*)g,
        (__attribute__((address_space(3))) void*)l,
        16, 0, 0);
}

// ==================== phase bodies (shared by mega + fallback) ====================

// P1: blocks 0..255 convert W1,W2 -> bf16 + zero T,Z; block 256: counting sort.
__device__ __forceinline__ void phase_prep(int blk, int tid, char* smem,
    const float* __restrict__ W1w, const float* __restrict__ W2w,
    unsigned short* __restrict__ Wb, float* __restrict__ T, float* __restrict__ Z,
    const int* __restrict__ label, int* __restrict__ cnt, int* __restrict__ offs,
    int* __restrict__ rowlist)
{
    if (blk < 256) {
        int lin = blk * 256 + tid;                 // 0..65535
        int i = lin * 8;
        const float* src = (i < D_OUT * D_IN) ? (W1w + i) : (W2w + (i - D_OUT * D_IN));
        float4 a = *(const float4*)(src);
        float4 b = *(const float4*)(src + 4);
        cvt8(a, b, Wb + i);
        if (lin < D_IN) T[lin] = 0.f;
        *(float4*)(Z + (size_t)lin * 4) = float4{0.f, 0.f, 0.f, 0.f};
    } else if (blk == 256) {
        // single-block counting sort, 256 threads x 64 labels each
        int* hA = (int*)smem;        // 1024 hist / cursor
        int* hB = hA + 1024;         // 256-entry scan buffer
#pragma unroll
        for (int q = 0; q < 4; ++q) hA[q * 256 + tid] = 0;
        __syncthreads();
        for (int r = 0; r < 64; ++r)
            atomicAdd(&hA[label[r * 256 + tid]], 1);
        __syncthreads();
        int v0 = hA[tid * 4 + 0], v1 = hA[tid * 4 + 1];
        int v2 = hA[tid * 4 + 2], v3 = hA[tid * 4 + 3];
        int s1 = v0 + v1, s2 = s1 + v2, s3 = s2 + v3;
        hB[tid] = s3;
        __syncthreads();
        for (int off = 1; off < 256; off <<= 1) {   // Hillis-Steele over thread totals
            int mine = hB[tid];
            int add  = (tid >= off) ? hB[tid - off] : 0;
            __syncthreads();
            hB[tid] = mine + add;
            __syncthreads();
        }
        int ex = hB[tid] - s3;                      // exclusive thread prefix
        cnt[tid * 4 + 0] = v0; cnt[tid * 4 + 1] = v1;
        cnt[tid * 4 + 2] = v2; cnt[tid * 4 + 3] = v3;
        int e0 = ex, e1 = ex + v0, e2 = ex + s1, e3 = ex + s2;
        offs[tid * 4 + 0] = e0; offs[tid * 4 + 1] = e1;
        offs[tid * 4 + 2] = e2; offs[tid * 4 + 3] = e3;
        hA[tid * 4 + 0] = e0; hA[tid * 4 + 1] = e1;   // cursor
        hA[tid * 4 + 2] = e2; hA[tid * 4 + 3] = e3;
        __syncthreads();
        for (int r = 0; r < 64; ++r) {
            int i0 = r * 256 + tid;
            int p = atomicAdd(&hA[label[i0]], 1);
            rowlist[p] = i0;
        }
    }
}

// P2: per-class column sums + xb emit; 2 classes per block, full 1024-col width.
__device__ __forceinline__ void phase_segsum(int blk, int tid,
    const float* __restrict__ x, const int* __restrict__ offs,
    const int* __restrict__ cnt, const int* __restrict__ rowlist,
    float* __restrict__ s, unsigned short* __restrict__ xb)
{
    int col = tid * 4;
    for (int c = blk * 2; c < blk * 2 + 2; ++c) {
        float4 acc = {0.f, 0.f, 0.f, 0.f};
        if (c < NCLS) {
            int o = offs[c], n = cnt[c];
            int r = 0;
            for (; r + 8 <= n; r += 8) {
                int idx[8];
#pragma unroll
                for (int u = 0; u < 8; ++u) idx[u] = rowlist[o + r + u];
                float4 v[8];
#pragma unroll
                for (int u = 0; u < 8; ++u)
                    v[u] = *(const float4*)(x + (size_t)idx[u] * D_IN + col);
#pragma unroll
                for (int u = 0; u < 8; ++u)
                    *(ushort4*)(xb + (size_t)idx[u] * D_IN + col) = f2bf4(v[u]);
#pragma unroll
                for (int u = 0; u < 8; ++u) {
                    acc.x += v[u].x; acc.y += v[u].y; acc.z += v[u].z; acc.w += v[u].w;
                }
            }
            for (; r < n; ++r) {
                int i0 = rowlist[o + r];
                float4 v = *(const float4*)(x + (size_t)i0 * D_IN + col);
                *(ushort4*)(xb + (size_t)i0 * D_IN + col) = f2bf4(v);
                acc.x += v.x; acc.y += v.y; acc.z += v.z; acc.w += v.w;
            }
        }
        *(float4*)(s + (size_t)c * D_IN + col) = acc;
    }
}

// P3: T = column sum of s (blocks 0..63, 64 atomics/address)
__device__ __forceinline__ void phase_tsum(int blk, int tid,
    const float* __restrict__ s, float* __restrict__ T)
{
    if (blk >= 64) return;
    int col = tid * 4;
    int c0 = blk * 16;
    float4 acc = {0.f, 0.f, 0.f, 0.f};
#pragma unroll 4
    for (int c = 0; c < 16; ++c) {
        float4 v = *(const float4*)(s + (size_t)(c0 + c) * D_IN + col);
        acc.x += v.x; acc.y += v.y; acc.z += v.z; acc.w += v.w;
    }
    atomicAdd(&T[col + 0], acc.x);
    atomicAdd(&T[col + 1], acc.y);
    atomicAdd(&T[col + 2], acc.z);
    atomicAdd(&T[col + 3], acc.w);
}

// P4: Z[c] += ((T - s_c)/d_c) @ W2^T (+ b2 in k-chunk 0). 512 items = 16m x 4n x 8k.
// Schedule per iter: cvt A -> reg-prefetch -> BARRIER -> async B(next) -> MFMA.
// (async issued AFTER the barrier: all waves' MFMA(it-1) reads of Bs[cur^1]
//  precede their barrier arrival, so the overwrite is race-free.)
__device__ __forceinline__ void phase_meanz(int blk, int tid, char* smem,
    const float* __restrict__ s, const float* __restrict__ T,
    const int* __restrict__ cnt, const unsigned short* __restrict__ Wb,
    const float* __restrict__ b2, float* __restrict__ Z)
{
    unsigned short* mAs = (unsigned short*)smem;   // [2][2048]
    unsigned short* mBs = mAs + 2 * 2048;          // [2][2048]

    const int wave = tid >> 6, lane = tid & 63;
    const int quad = lane >> 4, l16 = lane & 15;
    const int mt = blk & 15, nt = (blk >> 4) & 3, kt = blk >> 6;
    const int bm = mt * 64, bn = nt * 64, kb = kt * 128;
    const int wm = (wave >> 1) * 32, wn = (wave & 1) * 32;
    const int arow = tid >> 2, akc = (tid & 3) * 8;

    const int cls = bm + arow;
    const int d   = B - cnt[cls];
    const float scale = (d > 0) ? 1.f / (float)d : 0.f;
    const float* sp = s + (size_t)cls * D_IN + akc;
    const float* tp = T + akc;

    const int bidx = wave * 64 + lane;
    const int brow = bidx >> 2, bkc = (bidx & 3) * 8;
    const unsigned short* bp = Wb + (size_t)(256 + bn + brow) * D_IN + bkc;

    f32x4 acc[2][2] = {};

    float4 cs0 = *(const float4*)(sp + kb);
    float4 cs1 = *(const float4*)(sp + kb + 4);
    float4 ct0 = *(const float4*)(tp + kb);
    float4 ct1 = *(const float4*)(tp + kb + 4);
    async16(bp + kb, mBs + wave * 512);            // B(0) -> buf 0

    for (int it = 0; it < 4; ++it) {
        const int cur = it & 1;
        const int k0  = kb + it * 32;
        float4 m0 = {(ct0.x - cs0.x) * scale, (ct0.y - cs0.y) * scale,
                     (ct0.z - cs0.z) * scale, (ct0.w - cs0.w) * scale};
        float4 m1 = {(ct1.x - cs1.x) * scale, (ct1.y - cs1.y) * scale,
                     (ct1.z - cs1.z) * scale, (ct1.w - cs1.w) * scale};
        cvt8(m0, m1, mAs + cur * 2048 + arow * 32 + akc);
        if (it < 3) {
            cs0 = *(const float4*)(sp + k0 + 32);
            cs1 = *(const float4*)(sp + k0 + 36);
            ct0 = *(const float4*)(tp + k0 + 32);
            ct1 = *(const float4*)(tp + k0 + 36);
        }
        __syncthreads();     // drains own async B(it) + A-cvt writes for all waves
        if (it < 3)
            async16(bp + k0 + 32, mBs + (cur ^ 1) * 2048 + wave * 512);

        bf16x8 af[2], bfr[2];
#pragma unroll
        for (int t2 = 0; t2 < 2; ++t2) {
            af[t2]  = *(const bf16x8*)&mAs[cur * 2048 + (wm + t2 * 16 + l16) * 32 + quad * 8];
            bfr[t2] = *(const bf16x8*)&mBs[cur * 2048 + (wn + t2 * 16 + l16) * 32 + quad * 8];
        }
#pragma unroll
        for (int i = 0; i < 2; ++i)
#pragma unroll
            for (int j = 0; j < 2; ++j)
                acc[i][j] = __builtin_amdgcn_mfma_f32_16x16x32_bf16(af[i], bfr[j], acc[i][j], 0, 0, 0);
    }

    const bool addb = (kt == 0);
#pragma unroll
    for (int j = 0; j < 2; ++j) {
        const int n = bn + wn + j * 16 + l16;
        const float bias = addb ? b2[n] : 0.f;
#pragma unroll
        for (int i = 0; i < 2; ++i)
#pragma unroll
            for (int r = 0; r < 4; ++r) {
                const int c = bm + wm + i * 16 + quad * 4 + r;
                atomicAdd(&Z[(size_t)c * D_OUT + n], acc[i][j][r] + bias);
            }
    }
}

// P5: out = xb @ W1b^T + b1 + Z[label]; 128x64 tile, BK=64, dbuf. 512 tiles.
__device__ __forceinline__ void phase_gemm1(int blk, int tid, char* smem,
    const unsigned short* __restrict__ xb, const unsigned short* __restrict__ Wb,
    const float* __restrict__ b1, const float* __restrict__ Z,
    const int* __restrict__ label, float* __restrict__ out)
{
    typedef unsigned short (*AsT)[2][128][32];   // [buf][half][row][col] 32 KB
    typedef unsigned short (*BsT)[2][64][32];    // 16 KB
    AsT As = (AsT)smem;
    BsT Bs = (BsT)(smem + 32768);

    const int wave = tid >> 6, lane = tid & 63;
    const int quad = lane >> 4, l16 = lane & 15;
    const int bx = blk & 127, by = blk >> 7;     // 128 x 4
    const int bm = bx * 128, bn = by * 64;
    const int wm = (wave >> 1) * 64, wn = (wave & 1) * 32;

    const unsigned short* aps[4];
#pragma unroll
    for (int rr = 0; rr < 4; ++rr) {
        int dd = rr * 256 + tid;
        int h = dd >> 9, r = (dd >> 2) & 127, c = dd & 3;
        aps[rr] = xb + (size_t)(bm + r) * D_IN + h * 32 + c * 8;
    }
    const unsigned short* bps[2];
#pragma unroll
    for (int rr = 0; rr < 2; ++rr) {
        int dd = rr * 256 + tid;
        int h = dd >> 8, r = (dd >> 2) & 63, c = dd & 3;
        bps[rr] = Wb + (size_t)(bn + r) * D_IN + h * 32 + c * 8;
    }

    f32x4 acc[4][2] = {};

    {
        unsigned short* ab = &As[0][0][0][0];
        unsigned short* bb = &Bs[0][0][0][0];
#pragma unroll
        for (int rr = 0; rr < 4; ++rr) async16(aps[rr], ab + rr * 2048 + wave * 512);
#pragma unroll
        for (int rr = 0; rr < 2; ++rr) async16(bps[rr], bb + rr * 2048 + wave * 512);
    }
    __syncthreads();

    for (int t = 0; t < 16; ++t) {
        const int cur = t & 1;
        if (t + 1 < 16) {
            const int k1 = (t + 1) * 64;
            unsigned short* ab = &As[cur ^ 1][0][0][0];
            unsigned short* bb = &Bs[cur ^ 1][0][0][0];
#pragma unroll
            for (int rr = 0; rr < 4; ++rr) async16(aps[rr] + k1, ab + rr * 2048 + wave * 512);
#pragma unroll
            for (int rr = 0; rr < 2; ++rr) async16(bps[rr] + k1, bb + rr * 2048 + wave * 512);
        }
#pragma unroll
        for (int ks = 0; ks < 2; ++ks) {
            bf16x8 af[4], bfr[2];
#pragma unroll
            for (int i = 0; i < 4; ++i)
                af[i] = *(const bf16x8*)&As[cur][ks][wm + i * 16 + l16][quad * 8];
#pragma unroll
            for (int j = 0; j < 2; ++j)
                bfr[j] = *(const bf16x8*)&Bs[cur][ks][wn + j * 16 + l16][quad * 8];
#pragma unroll
            for (int i = 0; i < 4; ++i)
#pragma unroll
                for (int j = 0; j < 2; ++j)
                    acc[i][j] = __builtin_amdgcn_mfma_f32_16x16x32_bf16(af[i], bfr[j], acc[i][j], 0, 0, 0);
        }
        __syncthreads();   // after MFMA: safe for next stage to overwrite cur^1
    }

    int zrow[4][4];
#pragma unroll
    for (int i = 0; i < 4; ++i)
#pragma unroll
        for (int r = 0; r < 4; ++r)
            zrow[i][r] = label[bm + wm + i * 16 + quad * 4 + r] * D_OUT;

#pragma unroll
    for (int j = 0; j < 2; ++j) {
        const int n = bn + wn + j * 16 + l16;
        const float bias = b1[n];
#pragma unroll
        for (int i = 0; i < 4; ++i)
#pragma unroll
            for (int r = 0; r < 4; ++r) {
                const int m = bm + wm + i * 16 + quad * 4 + r;
                out[(size_t)m * D_OUT + n] = acc[i][j][r] + bias + Z[zrow[i][r] + n];
            }
    }
}

// ==================== mega (cooperative) ====================
__global__ __launch_bounds__(256, 2)
void mega_kernel(const float* __restrict__ x, const int* __restrict__ label,
                 const float* __restrict__ W1w, const float* __restrict__ b1,
                 const float* __restrict__ W2w, const float* __restrict__ b2,
                 float* __restrict__ out,
                 unsigned short* __restrict__ xb, unsigned short* __restrict__ Wb,
                 float* __restrict__ s, float* __restrict__ Z, float* __restrict__ T,
                 int* __restrict__ cnt, int* __restrict__ offs, int* __restrict__ rowlist)
{
    cg::grid_group grid = cg::this_grid();
    __shared__ __align__(16) char smem[49152];
    const int tid = threadIdx.x;
    const int blk = blockIdx.x;

    phase_prep(blk, tid, smem, W1w, W2w, Wb, T, Z, label, cnt, offs, rowlist);
    grid.sync();
    phase_segsum(blk, tid, x, offs, cnt, rowlist, s, xb);
    grid.sync();
    phase_tsum(blk, tid, s, T);
    grid.sync();
    phase_meanz(blk, tid, smem, s, T, cnt, Wb, b2, Z);
    grid.sync();
    phase_gemm1(blk, tid, smem, xb, Wb, b1, Z, label, out);
}

// ==================== fallback wrappers (plain launches) ====================
__global__ __launch_bounds__(256) void prep_fb(const float* W1w, const float* W2w,
    unsigned short* Wb, float* T, float* Z, const int* label,
    int* cnt, int* offs, int* rowlist) {
    __shared__ __align__(16) char smem[16384];
    phase_prep(blockIdx.x, threadIdx.x, smem, W1w, W2w, Wb, T, Z, label, cnt, offs, rowlist);
}
__global__ __launch_bounds__(256) void segsum_fb(const float* x, const int* offs,
    const int* cnt, const int* rowlist, float* s, unsigned short* xb) {
    phase_segsum(blockIdx.x, threadIdx.x, x, offs, cnt, rowlist, s, xb);
}
__global__ __launch_bounds__(256) void tsum_fb(const float* s, float* T) {
    phase_tsum(blockIdx.x, threadIdx.x, s, T);
}
__global__ __launch_bounds__(256) void meanz_fb(const float* s, const float* T,
    const int* cnt, const unsigned short* Wb, const float* b2, float* Z) {
    __shared__ __align__(16) char smem[16384];
    phase_meanz(blockIdx.x, threadIdx.x, smem, s, T, cnt, Wb, b2, Z);
}
__global__ __launch_bounds__(256) void gemm1_fb(const unsigned short* xb,
    const unsigned short* Wb, const float* b1, const float* Z,
    const int* label, float* out) {
    __shared__ __align__(16) char smem[49152];
    phase_gemm1(blockIdx.x, threadIdx.x, smem, xb, Wb, b1, Z, label, out);
}

// ---------------- launcher ----------------
extern "C" void kernel_launch(void* const* d_in, const int* in_sizes, int n_in,
                              void* d_out, int out_size, void* d_ws, size_t ws_size,
                              hipStream_t stream) {
    const float* x    = (const float*)d_in[0];
    const int*   lab  = (const int*)d_in[1];
    const float* W1_w = (const float*)d_in[2];
    const float* W1_b = (const float*)d_in[3];
    const float* W2_w = (const float*)d_in[4];
    const float* W2_b = (const float*)d_in[5];
    float* out = (float*)d_out;

    char* ws = (char*)d_ws;
    unsigned short* xb = (unsigned short*)(ws + OFF_XB);
    unsigned short* Wb = (unsigned short*)(ws + OFF_WB);
    float* s   = (float*)(ws + OFF_S);
    float* Z   = (float*)(ws + OFF_Z);
    float* T   = (float*)(ws + OFF_T);
    int* cnt     = (int*)(ws + OFF_CNT);
    int* offs    = (int*)(ws + OFF_OFFS);
    int* rowlist = (int*)(ws + OFF_ROWL);

    void* args[] = { (void*)&x, (void*)&lab, (void*)&W1_w, (void*)&W1_b,
                     (void*)&W2_w, (void*)&W2_b, (void*)&out,
                     (void*)&xb, (void*)&Wb, (void*)&s, (void*)&Z, (void*)&T,
                     (void*)&cnt, (void*)&offs, (void*)&rowlist };

    hipError_t err = hipLaunchCooperativeKernel(mega_kernel, dim3(512), dim3(256),
                                                args, 0, stream);
    if (err != hipSuccess) {
        (void)hipGetLastError();   // clear sticky error; fall back to 5 plain launches
        prep_fb<<<257, 256, 0, stream>>>(W1_w, W2_w, Wb, T, Z, lab, cnt, offs, rowlist);
        segsum_fb<<<512, 256, 0, stream>>>(x, offs, cnt, rowlist, s, xb);
        tsum_fb<<<64, 256, 0, stream>>>(s, T);
        meanz_fb<<<512, 256, 0, stream>>>(s, T, cnt, Wb, W2_b, Z);
        gemm1_fb<<<512, 256, 0, stream>>>(xb, Wb, W1_b, Z, lab, out);
    }
}

// Round 6
// 183.456 us; speedup vs baseline: 2.1962x; 2.1962x over previous
//
#include <hip/hip_runtime.h>

// Problem constants
constexpr int B      = 16384;
constexpr int D_IN   = 1024;
constexpr int D_OUT  = 256;
constexpr int NCLS   = 1000;

// ---------------- workspace layout (byte offsets) ----------------
constexpr size_t OFF_XB  = 0;                                   // B*D_IN bf16      (32 MB)
constexpr size_t OFF_WB  = OFF_XB + (size_t)B * D_IN * 2;       // 512*D_IN bf16    (1 MB)
constexpr size_t OFF_Y1  = OFF_WB + (size_t)512 * D_IN * 2;     // B*D_OUT f32      (16 MB)
constexpr size_t OFF_V   = OFF_Y1 + (size_t)B * D_OUT * 4;      // 1024*D_OUT f32   (1 MB, zeroed)
constexpr size_t OFF_U   = OFF_V  + (size_t)1024 * D_OUT * 4;   // D_OUT f32 (zeroed)
constexpr size_t OFF_CNT = OFF_U  + 4096;                       // 1024 int

typedef short bf16x8 __attribute__((ext_vector_type(8)));
typedef float f32x4  __attribute__((ext_vector_type(4)));

// fp32 -> bf16 round-to-nearest-even
__device__ __forceinline__ unsigned short f2bf(float f) {
    unsigned int u = __float_as_uint(f);
    return (unsigned short)((u + 0x7FFFu + ((u >> 16) & 1u)) >> 16);
}

__device__ __forceinline__ void cvt8(const float4& a, const float4& b, unsigned short* dst) {
    union { unsigned short u[8]; bf16x8 v; } r;
    r.u[0] = f2bf(a.x); r.u[1] = f2bf(a.y); r.u[2] = f2bf(a.z); r.u[3] = f2bf(a.w);
    r.u[4] = f2bf(b.x); r.u[5] = f2bf(b.y); r.u[6] = f2bf(b.z); r.u[7] = f2bf(b.w);
    *(bf16x8*)dst = r.v;
}

// async global->LDS, 16B/lane; lds dst = wave-uniform base (+lane*16 implied by HW)
__device__ __forceinline__ void async16(const unsigned short* g, unsigned short* l) {
    __builtin_amdgcn_global_load_lds(
        (const __attribute__((address_space(1))) void*)g,
        (__attribute__((address_space(3))) void*)l,
        16, 0, 0);
}

// ---- K0: convert x->xb, [W1;W2]->Wb (bf16); zero V,U; label histogram ----
constexpr int XCVT_BLKS = 8192;   // 8192*256 threads * 8 elems = 16.7M = B*D_IN
constexpr int WCVT_BLKS = 256;    // 256*256*8 = 512K = 512*D_IN
constexpr int VZ_BLKS   = 64;     // 64*256*16 = 256K floats = 1024*D_OUT
__global__ __launch_bounds__(256)
void prep_kernel(const float* __restrict__ x,
                 const float* __restrict__ W1, const float* __restrict__ W2,
                 const int* __restrict__ label,
                 unsigned short* __restrict__ xb, unsigned short* __restrict__ Wb,
                 float* __restrict__ V, float* __restrict__ U, int* __restrict__ cnt) {
    const int blk = blockIdx.x, tid = threadIdx.x;
    if (blk < XCVT_BLKS) {
        size_t lin = (size_t)blk * 256 + tid;
        const float* src = x + lin * 8;
        float4 a = *(const float4*)src;
        float4 b = *(const float4*)(src + 4);
        cvt8(a, b, xb + lin * 8);
    } else if (blk < XCVT_BLKS + WCVT_BLKS) {
        int lin = (blk - XCVT_BLKS) * 256 + tid;
        int i = lin * 8;
        const float* src = (i < D_OUT * D_IN) ? (W1 + i) : (W2 + (i - D_OUT * D_IN));
        float4 a = *(const float4*)src;
        float4 b = *(const float4*)(src + 4);
        cvt8(a, b, Wb + i);
    } else if (blk < XCVT_BLKS + WCVT_BLKS + VZ_BLKS) {
        int lb = blk - (XCVT_BLKS + WCVT_BLKS);
        int base = (lb * 256 + tid) * 16;
#pragma unroll
        for (int q = 0; q < 4; ++q)
            *(float4*)(V + base + q * 4) = float4{0.f, 0.f, 0.f, 0.f};
        if (lb == 0 && tid < 64)
            *(float4*)(U + tid * 4) = float4{0.f, 0.f, 0.f, 0.f};
    } else {
        // single-block LDS histogram (labels in [0,1000))
        __shared__ int h[1024];
#pragma unroll
        for (int q = 0; q < 4; ++q) h[q * 256 + tid] = 0;
        __syncthreads();
        for (int r = 0; r < 64; ++r)
            atomicAdd(&h[label[r * 256 + tid]], 1);
        __syncthreads();
#pragma unroll
        for (int q = 0; q < 4; ++q) cnt[q * 256 + tid] = h[q * 256 + tid];
    }
}

// ---- K1: y = xb @ [W1b;W2b]^T (N=512). 128x64 tiles, BK=64, 1024 blocks (4/CU).
// by<4: write y1 tile (raw, no bias). by>=4: atomically fold y2 rows into V[label]
// + in-wave column reduction into U. XCD-swizzled: the 8 by-blocks sharing an
// A-panel land on the same XCD's L2 (bid%8 = XCD round-robin heuristic; decode
// is bijective, so correctness is mapping-independent).
__global__ __launch_bounds__(256)
void gemm_kernel(const unsigned short* __restrict__ xb,
                 const unsigned short* __restrict__ Wb,
                 const int* __restrict__ label,
                 float* __restrict__ y1,
                 float* __restrict__ V, float* __restrict__ U) {
    __shared__ unsigned short As[2][128][32];   // [K-half][row][col] 16 KB
    __shared__ unsigned short Bs[2][64][32];    //  8 KB

    const int tid  = threadIdx.x;
    const int bid  = blockIdx.x;
    const int xcd   = bid & 7;
    const int local = bid >> 3;              // 0..127
    const int bx = xcd * 16 + (local & 15);  // 0..127
    const int by = local >> 4;               // 0..7
    const int bm = bx * 128;
    const int bn = by * 64;                  // in [0,512)

    const int wave = tid >> 6, lane = tid & 63;
    const int quad = lane >> 4, l16 = lane & 15;
    const int wm = (wave >> 1) * 64;
    const int wn = (wave & 1) * 32;

    const unsigned short* aps[4];
#pragma unroll
    for (int rr = 0; rr < 4; ++rr) {
        int dd = rr * 256 + tid;
        int h = dd >> 9, r = (dd >> 2) & 127, c = dd & 3;
        aps[rr] = xb + (size_t)(bm + r) * D_IN + h * 32 + c * 8;
    }
    const unsigned short* bps[2];
#pragma unroll
    for (int rr = 0; rr < 2; ++rr) {
        int dd = rr * 256 + tid;
        int h = dd >> 8, r = (dd >> 2) & 63, c = dd & 3;
        bps[rr] = Wb + (size_t)(bn + r) * D_IN + h * 32 + c * 8;
    }

    f32x4 acc[4][2] = {};

    for (int k0 = 0; k0 < D_IN; k0 += 64) {
        __syncthreads();   // previous iteration's frag reads complete
#pragma unroll
        for (int rr = 0; rr < 4; ++rr)
            async16(aps[rr] + k0, &As[0][0][0] + rr * 2048 + wave * 512);
#pragma unroll
        for (int rr = 0; rr < 2; ++rr)
            async16(bps[rr] + k0, &Bs[0][0][0] + rr * 2048 + wave * 512);
        __syncthreads();   // vmcnt drain before frag reads

#pragma unroll
        for (int ks = 0; ks < 2; ++ks) {
            bf16x8 af[4], bfr[2];
#pragma unroll
            for (int i = 0; i < 4; ++i)
                af[i] = *(const bf16x8*)&As[ks][wm + i * 16 + l16][quad * 8];
#pragma unroll
            for (int j = 0; j < 2; ++j)
                bfr[j] = *(const bf16x8*)&Bs[ks][wn + j * 16 + l16][quad * 8];
#pragma unroll
            for (int i = 0; i < 4; ++i)
#pragma unroll
                for (int j = 0; j < 2; ++j)
                    acc[i][j] = __builtin_amdgcn_mfma_f32_16x16x32_bf16(af[i], bfr[j], acc[i][j], 0, 0, 0);
        }
    }

    if (by < 4) {
        // y1 tile store (no bias; K2 adds it)
#pragma unroll
        for (int j = 0; j < 2; ++j) {
            const int n = bn + wn + j * 16 + l16;
#pragma unroll
            for (int i = 0; i < 4; ++i)
#pragma unroll
                for (int r = 0; r < 4; ++r) {
                    const int m = bm + wm + i * 16 + quad * 4 + r;
                    y1[(size_t)m * D_OUT + n] = acc[i][j][r];
                }
        }
    } else {
        // y2 tile: segment-sum into V[label], column-sum into U
        int lab[4][4];
#pragma unroll
        for (int i = 0; i < 4; ++i)
#pragma unroll
            for (int r = 0; r < 4; ++r)
                lab[i][r] = label[bm + wm + i * 16 + quad * 4 + r] * D_OUT;

        const int nb = bn - 256;
#pragma unroll
        for (int j = 0; j < 2; ++j) {
            const int n = nb + wn + j * 16 + l16;
            float cs = 0.f;
#pragma unroll
            for (int i = 0; i < 4; ++i)
#pragma unroll
                for (int r = 0; r < 4; ++r) {
                    float v = acc[i][j][r];
                    cs += v;
                    atomicAdd(&V[lab[i][r] + n], v);
                }
            cs += __shfl_xor(cs, 16);
            cs += __shfl_xor(cs, 32);   // 64-row column sum of this wave's tile
            if (quad == 0) atomicAdd(&U[n], cs);
        }
    }
}

// ---- K2: out[i] = y1[i] + b1 + b2 + (U - V[label_i]) / (B - cnt[label_i]) ----
__global__ __launch_bounds__(256)
void epi_kernel(const float* __restrict__ y1, const float* __restrict__ V,
                const float* __restrict__ U,
                const float* __restrict__ b1, const float* __restrict__ b2,
                const int* __restrict__ cnt, const int* __restrict__ label,
                float* __restrict__ out) {
    const int tid = threadIdx.x;
    const int row = blockIdx.x * 64 + (tid >> 2);
    const int lab = label[row];
    const float inv = 1.0f / (float)(B - cnt[lab]);
    const float* yp = y1 + (size_t)row * D_OUT;
    const float* vp = V  + (size_t)lab * D_OUT;
    float* op = out + (size_t)row * D_OUT;
    const int c0 = (tid & 3) * 4;
#pragma unroll
    for (int it = 0; it < 16; ++it) {
        const int c = c0 + it * 16;
        float4 y = *(const float4*)(yp + c);
        float4 v = *(const float4*)(vp + c);
        float4 u = *(const float4*)(U + c);
        float4 a1 = *(const float4*)(b1 + c);
        float4 a2 = *(const float4*)(b2 + c);
        float4 o;
        o.x = y.x + a1.x + a2.x + (u.x - v.x) * inv;
        o.y = y.y + a1.y + a2.y + (u.y - v.y) * inv;
        o.z = y.z + a1.z + a2.z + (u.z - v.z) * inv;
        o.w = y.w + a1.w + a2.w + (u.w - v.w) * inv;
        *(float4*)(op + c) = o;
    }
}

// ---------------- launcher ----------------
extern "C" void kernel_launch(void* const* d_in, const int* in_sizes, int n_in,
                              void* d_out, int out_size, void* d_ws, size_t ws_size,
                              hipStream_t stream) {
    const float* x    = (const float*)d_in[0];
    const int*   lab  = (const int*)d_in[1];
    const float* W1_w = (const float*)d_in[2];
    const float* W1_b = (const float*)d_in[3];
    const float* W2_w = (const float*)d_in[4];
    const float* W2_b = (const float*)d_in[5];
    float* out = (float*)d_out;

    char* ws = (char*)d_ws;
    unsigned short* xb = (unsigned short*)(ws + OFF_XB);
    unsigned short* Wb = (unsigned short*)(ws + OFF_WB);
    float* y1 = (float*)(ws + OFF_Y1);
    float* V  = (float*)(ws + OFF_V);
    float* U  = (float*)(ws + OFF_U);
    int*   cnt = (int*)(ws + OFF_CNT);

    // K0: convert + zero + histogram (streaming, one dispatch)
    prep_kernel<<<XCVT_BLKS + WCVT_BLKS + VZ_BLKS + 1, 256, 0, stream>>>(
        x, W1_w, W2_w, lab, xb, Wb, V, U, cnt);
    // K1: 512-wide GEMM; y1 stored, y2 folded into V/U
    gemm_kernel<<<1024, 256, 0, stream>>>(xb, Wb, lab, y1, V, U);
    // K2: epilogue
    epi_kernel<<<B / 64, 256, 0, stream>>>(y1, V, U, W1_b, W2_b, cnt, lab, out);
}

// Round 7
// 160.054 us; speedup vs baseline: 2.5173x; 1.1462x over previous
//
#include <hip/hip_runtime.h>

// Problem constants
constexpr int B      = 16384;
constexpr int D_IN   = 1024;
constexpr int D_OUT  = 256;
constexpr int NCLS   = 1000;

// ---------------- workspace layout (byte offsets) ----------------
constexpr size_t OFF_XB  = 0;                                   // B*D_IN bf16      (32 MB)
constexpr size_t OFF_WB  = OFF_XB + (size_t)B * D_IN * 2;       // 512*D_IN bf16    (1 MB)
constexpr size_t OFF_Y1  = OFF_WB + (size_t)512 * D_IN * 2;     // B*D_OUT f32      (16 MB)
constexpr size_t OFF_V   = OFF_Y1 + (size_t)B * D_OUT * 4;      // 1024*D_OUT f32   (1 MB, zeroed)
constexpr size_t OFF_U   = OFF_V  + (size_t)1024 * D_OUT * 4;   // D_OUT f32 (zeroed)
constexpr size_t OFF_CNT = OFF_U  + 4096;                       // 1024 int

typedef short bf16x8 __attribute__((ext_vector_type(8)));
typedef float f32x4  __attribute__((ext_vector_type(4)));

// fp32 -> bf16 round-to-nearest-even
__device__ __forceinline__ unsigned short f2bf(float f) {
    unsigned int u = __float_as_uint(f);
    return (unsigned short)((u + 0x7FFFu + ((u >> 16) & 1u)) >> 16);
}

__device__ __forceinline__ void cvt8(const float4& a, const float4& b, unsigned short* dst) {
    union { unsigned short u[8]; bf16x8 v; } r;
    r.u[0] = f2bf(a.x); r.u[1] = f2bf(a.y); r.u[2] = f2bf(a.z); r.u[3] = f2bf(a.w);
    r.u[4] = f2bf(b.x); r.u[5] = f2bf(b.y); r.u[6] = f2bf(b.z); r.u[7] = f2bf(b.w);
    *(bf16x8*)dst = r.v;
}

// async global->LDS, 16B/lane; lds dst = wave-uniform base (+lane*16 implied by HW)
__device__ __forceinline__ void async16(const unsigned short* g, unsigned short* l) {
    __builtin_amdgcn_global_load_lds(
        (const __attribute__((address_space(1))) void*)g,
        (__attribute__((address_space(3))) void*)l,
        16, 0, 0);
}

// ---- K0: blk0 = histogram (first, hides under stream); then x->xb, W->Wb, zero V/U ----
constexpr int XCVT_BLKS = 4096;   // 4096*256 thr * 16 elems = 16.7M = B*D_IN
constexpr int WCVT_BLKS = 128;    // 128*256*16 = 512K = 512*D_IN
constexpr int VZ_BLKS   = 64;     // 64*256*16  = 256K floats = 1024*D_OUT
__global__ __launch_bounds__(256)
void prep_kernel(const float* __restrict__ x,
                 const float* __restrict__ W1, const float* __restrict__ W2,
                 const int* __restrict__ label,
                 unsigned short* __restrict__ xb, unsigned short* __restrict__ Wb,
                 float* __restrict__ V, float* __restrict__ U, int* __restrict__ cnt) {
    const int blk = blockIdx.x, tid = threadIdx.x;
    if (blk == 0) {
        // LDS histogram; 64 labels/thread, 16-deep load batches (pipelined)
        __shared__ int h[1024];
#pragma unroll
        for (int q = 0; q < 4; ++q) h[q * 256 + tid] = 0;
        __syncthreads();
        for (int base = 0; base < 64; base += 16) {
            int lv[16];
#pragma unroll
            for (int u = 0; u < 16; ++u) lv[u] = label[(base + u) * 256 + tid];
#pragma unroll
            for (int u = 0; u < 16; ++u) atomicAdd(&h[lv[u]], 1);
        }
        __syncthreads();
#pragma unroll
        for (int q = 0; q < 4; ++q) cnt[q * 256 + tid] = h[q * 256 + tid];
    } else if (blk <= XCVT_BLKS) {
        size_t lin = (size_t)(blk - 1) * 256 + tid;    // 16 floats / thread
        const float* src = x + lin * 16;
        float4 a0 = *(const float4*)(src);
        float4 a1 = *(const float4*)(src + 4);
        float4 a2 = *(const float4*)(src + 8);
        float4 a3 = *(const float4*)(src + 12);
        cvt8(a0, a1, xb + lin * 16);
        cvt8(a2, a3, xb + lin * 16 + 8);
    } else if (blk <= XCVT_BLKS + WCVT_BLKS) {
        int lin = (blk - 1 - XCVT_BLKS) * 256 + tid;
        int i = lin * 16;                              // 262144 % 16 == 0: no W1/W2 straddle
        const float* src = (i < D_OUT * D_IN) ? (W1 + i) : (W2 + (i - D_OUT * D_IN));
        float4 a0 = *(const float4*)(src);
        float4 a1 = *(const float4*)(src + 4);
        float4 a2 = *(const float4*)(src + 8);
        float4 a3 = *(const float4*)(src + 12);
        cvt8(a0, a1, Wb + i);
        cvt8(a2, a3, Wb + i + 8);
    } else {
        int lb = blk - 1 - XCVT_BLKS - WCVT_BLKS;
        int base = (lb * 256 + tid) * 16;
#pragma unroll
        for (int q = 0; q < 4; ++q)
            *(float4*)(V + base + q * 4) = float4{0.f, 0.f, 0.f, 0.f};
        if (lb == 0 && tid < 64)
            *(float4*)(U + tid * 4) = float4{0.f, 0.f, 0.f, 0.f};
    }
}

// ---- K1: y = xb @ [W1b;W2b]^T (N=512). 128x128 tiles, BK=64, 512 blocks.
// Wave-tile 64x64 -> 32 MFMA per barrier-pair. LDS rows are full-BK (64 shorts,
// 128B) with slot-XOR swizzle (slot ^= row&7): global_load_lds writes linearly,
// the SOURCE address is pre-swizzled, reads apply the same XOR -> 2 lanes/bank.
// XCD-pinned: bid&7 = XCD; each XCD gets 16 consecutive bx (4MB of A panels = L2).
// by<2: store y1 tile. by>=2: fold y2 into V[label] (atomics) + column-sum into U.
__global__ __launch_bounds__(256)
void gemm_kernel(const unsigned short* __restrict__ xb,
                 const unsigned short* __restrict__ Wb,
                 const int* __restrict__ label,
                 float* __restrict__ y1,
                 float* __restrict__ V, float* __restrict__ U) {
    __shared__ unsigned short As[128][64];   // 16 KB, slot-swizzled full-BK rows
    __shared__ unsigned short Bs[128][64];   // 16 KB

    const int tid  = threadIdx.x;
    const int bid  = blockIdx.x;
    const int xcd   = bid & 7;
    const int local = bid >> 3;              // 0..63
    const int bx = xcd * 16 + (local & 15);  // 0..127
    const int by = local >> 4;               // 0..3
    const int bm = bx * 128;
    const int bn = by * 128;                 // in [0,512)

    const int wave = tid >> 6, lane = tid & 63;
    const int quad = lane >> 4, l16 = lane & 15;
    const int wm = (wave >> 1) * 64;
    const int wn = (wave & 1) * 64;
    const int sx = l16 & 7;                  // read-side XOR (row&7 == l16&7)

    // staging: 1024 chunks of 16B each for A and B (4 rounds x 256 threads).
    // chunk dd -> LDS (row=dd>>3, slot=dd&7); source k-chunk = slot ^ (row&7).
    const unsigned short* aps[4];
    const unsigned short* bps[4];
#pragma unroll
    for (int rr = 0; rr < 4; ++rr) {
        int dd = rr * 256 + tid;
        int r = dd >> 3, sl = dd & 7;
        int sc = sl ^ (r & 7);
        aps[rr] = xb + (size_t)(bm + r) * D_IN + sc * 8;
        bps[rr] = Wb + (size_t)(bn + r) * D_IN + sc * 8;
    }

    f32x4 acc[4][4] = {};

    for (int k0 = 0; k0 < D_IN; k0 += 64) {
        __syncthreads();   // previous iteration's frag reads complete
#pragma unroll
        for (int rr = 0; rr < 4; ++rr)
            async16(aps[rr] + k0, &As[0][0] + rr * 2048 + wave * 512);
#pragma unroll
        for (int rr = 0; rr < 4; ++rr)
            async16(bps[rr] + k0, &Bs[0][0] + rr * 2048 + wave * 512);
        __syncthreads();   // vmcnt drain before frag reads

#pragma unroll
        for (int ks = 0; ks < 2; ++ks) {
            const int s = ks * 4 + quad;
            bf16x8 af[4], bfr[4];
#pragma unroll
            for (int i = 0; i < 4; ++i)
                af[i] = *(const bf16x8*)&As[wm + i * 16 + l16][((s ^ sx) * 8)];
#pragma unroll
            for (int j = 0; j < 4; ++j)
                bfr[j] = *(const bf16x8*)&Bs[wn + j * 16 + l16][((s ^ sx) * 8)];
#pragma unroll
            for (int i = 0; i < 4; ++i)
#pragma unroll
                for (int j = 0; j < 4; ++j)
                    acc[i][j] = __builtin_amdgcn_mfma_f32_16x16x32_bf16(af[i], bfr[j], acc[i][j], 0, 0, 0);
        }
    }

    if (by < 2) {
        // y1 tile store (raw; K2 adds biases)
#pragma unroll
        for (int j = 0; j < 4; ++j) {
            const int n = bn + wn + j * 16 + l16;
#pragma unroll
            for (int i = 0; i < 4; ++i)
#pragma unroll
                for (int r = 0; r < 4; ++r) {
                    const int m = bm + wm + i * 16 + quad * 4 + r;
                    y1[(size_t)m * D_OUT + n] = acc[i][j][r];
                }
        }
    } else {
        // y2 tile: segment-sum into V[label], column-sum into U
        int lab[4][4];
#pragma unroll
        for (int i = 0; i < 4; ++i)
#pragma unroll
            for (int r = 0; r < 4; ++r)
                lab[i][r] = label[bm + wm + i * 16 + quad * 4 + r] * D_OUT;

        const int nb = bn - 256;
#pragma unroll
        for (int j = 0; j < 4; ++j) {
            const int n = nb + wn + j * 16 + l16;
            float cs = 0.f;
#pragma unroll
            for (int i = 0; i < 4; ++i)
#pragma unroll
                for (int r = 0; r < 4; ++r) {
                    float v = acc[i][j][r];
                    cs += v;
                    atomicAdd(&V[lab[i][r] + n], v);
                }
            cs += __shfl_xor(cs, 16);
            cs += __shfl_xor(cs, 32);   // sum over the 4 quads -> 64-row column sum
            if (quad == 0) atomicAdd(&U[n], cs);
        }
    }
}

// ---- K2: out[i] = y1[i] + b1 + b2 + (U - V[label_i]) / (B - cnt[label_i]) ----
__global__ __launch_bounds__(256)
void epi_kernel(const float* __restrict__ y1, const float* __restrict__ V,
                const float* __restrict__ U,
                const float* __restrict__ b1, const float* __restrict__ b2,
                const int* __restrict__ cnt, const int* __restrict__ label,
                float* __restrict__ out) {
    const int tid = threadIdx.x;
    const int row = blockIdx.x * 64 + (tid >> 2);
    const int lab = label[row];
    const float inv = 1.0f / (float)(B - cnt[lab]);
    const float* yp = y1 + (size_t)row * D_OUT;
    const float* vp = V  + (size_t)lab * D_OUT;
    float* op = out + (size_t)row * D_OUT;
    const int c0 = (tid & 3) * 4;
#pragma unroll
    for (int it = 0; it < 16; ++it) {
        const int c = c0 + it * 16;
        float4 y = *(const float4*)(yp + c);
        float4 v = *(const float4*)(vp + c);
        float4 u = *(const float4*)(U + c);
        float4 a1 = *(const float4*)(b1 + c);
        float4 a2 = *(const float4*)(b2 + c);
        float4 o;
        o.x = y.x + a1.x + a2.x + (u.x - v.x) * inv;
        o.y = y.y + a1.y + a2.y + (u.y - v.y) * inv;
        o.z = y.z + a1.z + a2.z + (u.z - v.z) * inv;
        o.w = y.w + a1.w + a2.w + (u.w - v.w) * inv;
        *(float4*)(op + c) = o;
    }
}

// ---------------- launcher ----------------
extern "C" void kernel_launch(void* const* d_in, const int* in_sizes, int n_in,
                              void* d_out, int out_size, void* d_ws, size_t ws_size,
                              hipStream_t stream) {
    const float* x    = (const float*)d_in[0];
    const int*   lab  = (const int*)d_in[1];
    const float* W1_w = (const float*)d_in[2];
    const float* W1_b = (const float*)d_in[3];
    const float* W2_w = (const float*)d_in[4];
    const float* W2_b = (const float*)d_in[5];
    float* out = (float*)d_out;

    char* ws = (char*)d_ws;
    unsigned short* xb = (unsigned short*)(ws + OFF_XB);
    unsigned short* Wb = (unsigned short*)(ws + OFF_WB);
    float* y1 = (float*)(ws + OFF_Y1);
    float* V  = (float*)(ws + OFF_V);
    float* U  = (float*)(ws + OFF_U);
    int*   cnt = (int*)(ws + OFF_CNT);

    // K0: hist (block 0, runs under the stream) + convert + zero
    prep_kernel<<<1 + XCVT_BLKS + WCVT_BLKS + VZ_BLKS, 256, 0, stream>>>(
        x, W1_w, W2_w, lab, xb, Wb, V, U, cnt);
    // K1: 512-wide GEMM; y1 stored, y2 folded into V/U
    gemm_kernel<<<512, 256, 0, stream>>>(xb, Wb, lab, y1, V, U);
    // K2: epilogue
    epi_kernel<<<B / 64, 256, 0, stream>>>(y1, V, U, W1_b, W2_b, cnt, lab, out);
}

// Round 8
// 148.824 us; speedup vs baseline: 2.7073x; 1.0755x over previous
//
#include <hip/hip_runtime.h>

// Problem constants
constexpr int B      = 16384;
constexpr int D_IN   = 1024;
constexpr int D_OUT  = 256;
constexpr int NCLS   = 1000;

// ---------------- workspace layout (byte offsets) ----------------
constexpr size_t OFF_WB  = 0;                                   // 512*D_IN bf16    (1 MB)
constexpr size_t OFF_Y1  = OFF_WB + (size_t)512 * D_IN * 2;     // B*D_OUT f32      (16 MB)
constexpr size_t OFF_V   = OFF_Y1 + (size_t)B * D_OUT * 4;      // 1024*D_OUT f32   (1 MB, zeroed)
constexpr size_t OFF_U   = OFF_V  + (size_t)1024 * D_OUT * 4;   // D_OUT f32 (zeroed)
constexpr size_t OFF_CNT = OFF_U  + 4096;                       // 1024 int

typedef short bf16x8 __attribute__((ext_vector_type(8)));
typedef float f32x4  __attribute__((ext_vector_type(4)));

// fp32 -> bf16 round-to-nearest-even (bit trick; used only in tiny W-convert)
__device__ __forceinline__ unsigned short f2bf(float f) {
    unsigned int u = __float_as_uint(f);
    return (unsigned short)((u + 0x7FFFu + ((u >> 16) & 1u)) >> 16);
}

__device__ __forceinline__ void cvt8(const float4& a, const float4& b, unsigned short* dst) {
    union { unsigned short u[8]; bf16x8 v; } r;
    r.u[0] = f2bf(a.x); r.u[1] = f2bf(a.y); r.u[2] = f2bf(a.z); r.u[3] = f2bf(a.w);
    r.u[4] = f2bf(b.x); r.u[5] = f2bf(b.y); r.u[6] = f2bf(b.z); r.u[7] = f2bf(b.w);
    *(bf16x8*)dst = r.v;
}

// HW packed f32->bf16 (RNE), 1 instr per 2 floats — keeps GEMM staging off the VALU wall
__device__ __forceinline__ unsigned int cvtpk(float lo, float hi) {
    unsigned int r;
    asm volatile("v_cvt_pk_bf16_f32 %0, %1, %2" : "=v"(r) : "v"(lo), "v"(hi));
    return r;
}

// async global->LDS, 16B/lane; lds dst = wave-uniform base (+lane*16 implied by HW)
__device__ __forceinline__ void async16(const unsigned short* g, unsigned short* l) {
    __builtin_amdgcn_global_load_lds(
        (const __attribute__((address_space(1))) void*)g,
        (__attribute__((address_space(3))) void*)l,
        16, 0, 0);
}

// ---- K0: blk0 = label histogram; blk 1..128 = W cvt; blk 129..192 = zero V,U ----
__global__ __launch_bounds__(256)
void prep_kernel(const float* __restrict__ W1, const float* __restrict__ W2,
                 const int* __restrict__ label,
                 unsigned short* __restrict__ Wb,
                 float* __restrict__ V, float* __restrict__ U, int* __restrict__ cnt) {
    const int blk = blockIdx.x, tid = threadIdx.x;
    if (blk == 0) {
        __shared__ int h[1024];
#pragma unroll
        for (int q = 0; q < 4; ++q) h[q * 256 + tid] = 0;
        __syncthreads();
        for (int base = 0; base < 64; base += 16) {
            int lv[16];
#pragma unroll
            for (int u = 0; u < 16; ++u) lv[u] = label[(base + u) * 256 + tid];
#pragma unroll
            for (int u = 0; u < 16; ++u) atomicAdd(&h[lv[u]], 1);
        }
        __syncthreads();
#pragma unroll
        for (int q = 0; q < 4; ++q) cnt[q * 256 + tid] = h[q * 256 + tid];
    } else if (blk <= 128) {
        int lin = (blk - 1) * 256 + tid;
        int i = lin * 16;                              // 262144 % 16 == 0: no W1/W2 straddle
        const float* src = (i < D_OUT * D_IN) ? (W1 + i) : (W2 + (i - D_OUT * D_IN));
        float4 a0 = *(const float4*)(src);
        float4 a1 = *(const float4*)(src + 4);
        float4 a2 = *(const float4*)(src + 8);
        float4 a3 = *(const float4*)(src + 12);
        cvt8(a0, a1, Wb + i);
        cvt8(a2, a3, Wb + i + 8);
    } else {
        int lb = blk - 129;                            // 0..63
        int base = (lb * 256 + tid) * 16;
#pragma unroll
        for (int q = 0; q < 4; ++q)
            *(float4*)(V + base + q * 4) = float4{0.f, 0.f, 0.f, 0.f};
        if (lb == 0 && tid < 64)
            *(float4*)(U + tid * 4) = float4{0.f, 0.f, 0.f, 0.f};
    }
}

// ---- K1: y = x @ [W1b;W2b]^T (N=512), A converted f32->bf16 in-register.
// 128x128 tiles, BK=64, 512 blocks (2/CU). Counted-vmcnt 2-phase pipeline:
//   t: [issue A(t+1) f32 loads] vmcnt(8) lgkmcnt(0) BARRIER sched_barrier
//      [async B(t+1)->Bs[nxt]]  (post-barrier: t-1's Bs[nxt] readers are done)
//      [ds_read frags(cur); 32 MFMA]  [cvtpk + ds_write As[nxt]]
// vmcnt(8): B(t)'s 4 asyncs are the oldest behind A(t+1)'s 8 loads -> B(t) landed.
// LDS: linear chunk layout, source column pre-swizzled (sc = sl^(row&7)), reads
// XOR'd -> bank-conflict-free (verified 0 conflicts in r7).
__global__ __launch_bounds__(256, 2)
void gemm_kernel(const float* __restrict__ x,
                 const unsigned short* __restrict__ Wb,
                 const int* __restrict__ label,
                 float* __restrict__ y1,
                 float* __restrict__ V, float* __restrict__ U) {
    __shared__ unsigned short As[2][128][64];   // 32 KB
    __shared__ unsigned short Bs[2][128][64];   // 32 KB

    const int tid  = threadIdx.x;
    const int bid  = blockIdx.x;
    const int xcd   = bid & 7;
    const int local = bid >> 3;              // 0..63
    const int bx = xcd * 16 + (local & 15);  // 0..127
    const int by = local >> 4;               // 0..3
    const int bm = bx * 128;
    const int bn = by * 128;                 // in [0,512)

    const int wave = tid >> 6, lane = tid & 63;
    const int quad = lane >> 4, l16 = lane & 15;
    const int wm = (wave >> 1) * 64;
    const int wn = (wave & 1) * 64;
    const int sx = l16 & 7;                  // read-side XOR

    // A: 1024 chunks (row=dd>>3, slot=dd&7), source k-col pre-swizzled
    const float* xps[4];
    int adst[4];
#pragma unroll
    for (int rr = 0; rr < 4; ++rr) {
        int dd = rr * 256 + tid;
        int r = dd >> 3, sl = dd & 7;
        int sc = sl ^ (r & 7);
        xps[rr] = x + (size_t)(bm + r) * D_IN + sc * 8;
        adst[rr] = dd * 8;                   // linear LDS offset in shorts
    }
    // B: 1024 chunks via global_load_lds (source pre-swizzled, dest linear)
    const unsigned short* bps[4];
#pragma unroll
    for (int rr = 0; rr < 4; ++rr) {
        int dd = rr * 256 + tid;
        int r = dd >> 3, sl = dd & 7;
        int sc = sl ^ (r & 7);
        bps[rr] = Wb + (size_t)(bn + r) * D_IN + sc * 8;
    }

    f32x4 acc[4][4] = {};
    float4 a0[4], a1[4];

    // ---- prologue: tile 0 ----
#pragma unroll
    for (int rr = 0; rr < 4; ++rr) {
        a0[rr] = *(const float4*)(xps[rr]);
        a1[rr] = *(const float4*)(xps[rr] + 4);
    }
#pragma unroll
    for (int rr = 0; rr < 4; ++rr)
        async16(bps[rr], &Bs[0][0][0] + rr * 2048 + wave * 512);
#pragma unroll
    for (int rr = 0; rr < 4; ++rr) {
        union { unsigned int w[4]; bf16x8 v; } p;
        p.w[0] = cvtpk(a0[rr].x, a0[rr].y);
        p.w[1] = cvtpk(a0[rr].z, a0[rr].w);
        p.w[2] = cvtpk(a1[rr].x, a1[rr].y);
        p.w[3] = cvtpk(a1[rr].z, a1[rr].w);
        *(bf16x8*)(&As[0][0][0] + adst[rr]) = p.v;
    }

    for (int t = 0; t < 16; ++t) {
        const int cur = t & 1;
        const int k1 = (t + 1) * 64;
        if (t < 15) {
            // issue A(t+1) f32 loads (8 per thread) — latency hides under MFMA(t)
#pragma unroll
            for (int rr = 0; rr < 4; ++rr) {
                a0[rr] = *(const float4*)(xps[rr] + k1);
                a1[rr] = *(const float4*)(xps[rr] + k1 + 4);
            }
            asm volatile("s_waitcnt vmcnt(8)" ::: "memory");   // B(t) landed
        } else {
            asm volatile("s_waitcnt vmcnt(0)" ::: "memory");
        }
        asm volatile("s_waitcnt lgkmcnt(0)" ::: "memory");     // As(cur) writes drained
        __builtin_amdgcn_s_barrier();
        __builtin_amdgcn_sched_barrier(0);
        if (t < 15) {
            // B(t+1) async AFTER barrier: t-1's readers of Bs[nxt] are provably done
#pragma unroll
            for (int rr = 0; rr < 4; ++rr)
                async16(bps[rr] + k1, &Bs[cur ^ 1][0][0] + rr * 2048 + wave * 512);
        }

        // compute tile t from buffers[cur]
#pragma unroll
        for (int ks = 0; ks < 2; ++ks) {
            const int s = ks * 4 + quad;
            bf16x8 af[4], bfr[4];
#pragma unroll
            for (int i = 0; i < 4; ++i)
                af[i] = *(const bf16x8*)&As[cur][wm + i * 16 + l16][((s ^ sx) * 8)];
#pragma unroll
            for (int j = 0; j < 4; ++j)
                bfr[j] = *(const bf16x8*)&Bs[cur][wn + j * 16 + l16][((s ^ sx) * 8)];
#pragma unroll
            for (int i = 0; i < 4; ++i)
#pragma unroll
                for (int j = 0; j < 4; ++j)
                    acc[i][j] = __builtin_amdgcn_mfma_f32_16x16x32_bf16(af[i], bfr[j], acc[i][j], 0, 0, 0);
        }

        if (t < 15) {
            // A(t+1) regs in (compiler inserts vmcnt(4): only B(t+1) behind them)
#pragma unroll
            for (int rr = 0; rr < 4; ++rr) {
                union { unsigned int w[4]; bf16x8 v; } p;
                p.w[0] = cvtpk(a0[rr].x, a0[rr].y);
                p.w[1] = cvtpk(a0[rr].z, a0[rr].w);
                p.w[2] = cvtpk(a1[rr].x, a1[rr].y);
                p.w[3] = cvtpk(a1[rr].z, a1[rr].w);
                *(bf16x8*)(&As[cur ^ 1][0][0] + adst[rr]) = p.v;
            }
        }
    }

    if (by < 2) {
        // y1 tile store (raw; K2 adds biases)
#pragma unroll
        for (int j = 0; j < 4; ++j) {
            const int n = bn + wn + j * 16 + l16;
#pragma unroll
            for (int i = 0; i < 4; ++i)
#pragma unroll
                for (int r = 0; r < 4; ++r) {
                    const int m = bm + wm + i * 16 + quad * 4 + r;
                    y1[(size_t)m * D_OUT + n] = acc[i][j][r];
                }
        }
    } else {
        // y2 tile: segment-sum into V[label], column-sum into U
        int lab[4][4];
#pragma unroll
        for (int i = 0; i < 4; ++i)
#pragma unroll
            for (int r = 0; r < 4; ++r)
                lab[i][r] = label[bm + wm + i * 16 + quad * 4 + r] * D_OUT;

        const int nb = bn - 256;
#pragma unroll
        for (int j = 0; j < 4; ++j) {
            const int n = nb + wn + j * 16 + l16;
            float cs = 0.f;
#pragma unroll
            for (int i = 0; i < 4; ++i)
#pragma unroll
                for (int r = 0; r < 4; ++r) {
                    float v = acc[i][j][r];
                    cs += v;
                    atomicAdd(&V[lab[i][r] + n], v);
                }
            cs += __shfl_xor(cs, 16);
            cs += __shfl_xor(cs, 32);   // 64-row column sum of this wave's tile
            if (quad == 0) atomicAdd(&U[n], cs);
        }
    }
}

// ---- K2: out[i] = y1[i] + b1 + b2 + (U - V[label_i]) / (B - cnt[label_i]) ----
__global__ __launch_bounds__(256)
void epi_kernel(const float* __restrict__ y1, const float* __restrict__ V,
                const float* __restrict__ U,
                const float* __restrict__ b1, const float* __restrict__ b2,
                const int* __restrict__ cnt, const int* __restrict__ label,
                float* __restrict__ out) {
    const int tid = threadIdx.x;
    const int row = blockIdx.x * 64 + (tid >> 2);
    const int lab = label[row];
    const float inv = 1.0f / (float)(B - cnt[lab]);
    const float* yp = y1 + (size_t)row * D_OUT;
    const float* vp = V  + (size_t)lab * D_OUT;
    float* op = out + (size_t)row * D_OUT;
    const int c0 = (tid & 3) * 4;
#pragma unroll
    for (int it = 0; it < 16; ++it) {
        const int c = c0 + it * 16;
        float4 y = *(const float4*)(yp + c);
        float4 v = *(const float4*)(vp + c);
        float4 u = *(const float4*)(U + c);
        float4 a1 = *(const float4*)(b1 + c);
        float4 a2 = *(const float4*)(b2 + c);
        float4 o;
        o.x = y.x + a1.x + a2.x + (u.x - v.x) * inv;
        o.y = y.y + a1.y + a2.y + (u.y - v.y) * inv;
        o.z = y.z + a1.z + a2.z + (u.z - v.z) * inv;
        o.w = y.w + a1.w + a2.w + (u.w - v.w) * inv;
        *(float4*)(op + c) = o;
    }
}

// ---------------- launcher ----------------
extern "C" void kernel_launch(void* const* d_in, const int* in_sizes, int n_in,
                              void* d_out, int out_size, void* d_ws, size_t ws_size,
                              hipStream_t stream) {
    const float* x    = (const float*)d_in[0];
    const int*   lab  = (const int*)d_in[1];
    const float* W1_w = (const float*)d_in[2];
    const float* W1_b = (const float*)d_in[3];
    const float* W2_w = (const float*)d_in[4];
    const float* W2_b = (const float*)d_in[5];
    float* out = (float*)d_out;

    char* ws = (char*)d_ws;
    unsigned short* Wb = (unsigned short*)(ws + OFF_WB);
    float* y1 = (float*)(ws + OFF_Y1);
    float* V  = (float*)(ws + OFF_V);
    float* U  = (float*)(ws + OFF_U);
    int*   cnt = (int*)(ws + OFF_CNT);

    // K0: hist + W cvt + zero V/U (tiny)
    prep_kernel<<<193, 256, 0, stream>>>(W1_w, W2_w, lab, Wb, V, U, cnt);
    // K1: 512-wide GEMM with in-register A conversion; y1 stored, y2 folded into V/U
    gemm_kernel<<<512, 256, 0, stream>>>(x, Wb, lab, y1, V, U);
    // K2: epilogue
    epi_kernel<<<B / 64, 256, 0, stream>>>(y1, V, U, W1_b, W2_b, cnt, lab, out);
}